// Round 4
// baseline (364.897 us; speedup 1.0000x reference)
//
#include <hip/hip_runtime.h>
#include <hip/hip_fp8.h>

#define LL 64
#define DD 1024
#define HH 512
#define SS 50000
#define VV 40000
#define KD 32
#define MM 128  // B*L

typedef __bf16 bf16_t;
typedef __bf16 bf16x8 __attribute__((ext_vector_type(8)));
typedef __bf16 bf16x4 __attribute__((ext_vector_type(4)));
typedef __bf16 bf16x2 __attribute__((ext_vector_type(2)));
typedef float f32x4 __attribute__((ext_vector_type(4)));

__device__ __forceinline__ void async_ld16(const void* g, void* l) {
    __builtin_amdgcn_global_load_lds(
        (const __attribute__((address_space(1))) void*)g,
        (__attribute__((address_space(3))) void*)l, 16, 0, 0);
}

// ---------------- Kernel 1: BatchNorm over (B, D) per l; write xn bf16 [128][1024]
__global__ __launch_bounds__(256) void k_bn(const float* __restrict__ x,
        const float* __restrict__ gamma, const float* __restrict__ beta,
        bf16_t* __restrict__ xn) {
    int l = blockIdx.x;        // 0..63
    int t = threadIdx.x;       // 0..255
    int b = t >> 7;            // 0..1
    int d0 = (t & 127) << 3;   // 8 elems/thread
    const float* xp = x + (size_t)(b * LL + l) * DD + d0;
    float4 v0 = *(const float4*)xp;
    float4 v1 = *(const float4*)(xp + 4);
    float s  = v0.x + v0.y + v0.z + v0.w + v1.x + v1.y + v1.z + v1.w;
    float ss = v0.x*v0.x + v0.y*v0.y + v0.z*v0.z + v0.w*v0.w
             + v1.x*v1.x + v1.y*v1.y + v1.z*v1.z + v1.w*v1.w;
    #pragma unroll
    for (int off = 32; off > 0; off >>= 1) {
        s  += __shfl_xor(s, off);
        ss += __shfl_xor(ss, off);
    }
    __shared__ float red[8];
    int wv = t >> 6, ln = t & 63;
    if (ln == 0) { red[wv] = s; red[4 + wv] = ss; }
    __syncthreads();
    float tot  = red[0] + red[1] + red[2] + red[3];
    float tots = red[4] + red[5] + red[6] + red[7];
    float mean = tot * (1.0f / 2048.0f);
    float var  = tots * (1.0f / 2048.0f) - mean * mean;
    float rstd = rsqrtf(var + 1e-5f);
    float g   = gamma[l] * rstd;
    float ofs = beta[l] - mean * g;
    bf16x8 o;
    o[0] = (bf16_t)(v0.x * g + ofs);
    o[1] = (bf16_t)(v0.y * g + ofs);
    o[2] = (bf16_t)(v0.z * g + ofs);
    o[3] = (bf16_t)(v0.w * g + ofs);
    o[4] = (bf16_t)(v1.x * g + ofs);
    o[5] = (bf16_t)(v1.y * g + ofs);
    o[6] = (bf16_t)(v1.z * g + ofs);
    o[7] = (bf16_t)(v1.w * g + ofs);
    *(bf16x8*)(xn + (size_t)(b * LL + l) * DD + d0) = o;
}

// ---------------- Kernel 2: h = relu(xn @ W1 + b1), bf16 [128][512]
// 256 blocks x 2 waves; waves split K (512 each), LDS reduce.
__global__ __launch_bounds__(128) void k_gemm1(const bf16_t* __restrict__ xn,
        const float* __restrict__ W1, const float* __restrict__ b1,
        bf16_t* __restrict__ h) {
    int t = threadIdx.x;
    int wv = t >> 6, lane = t & 63;
    int c = lane & 15, q = lane >> 4;
    int tile = blockIdx.x;           // 256 tiles: 8 m x 32 n
    int tm = tile >> 5, tn = tile & 31;
    int col = tn * 16 + c;
    f32x4 acc = {};
    for (int kk = wv * 512; kk < wv * 512 + 512; kk += 32) {
        bf16x8 afr = *(const bf16x8*)(xn + (size_t)(tm * 16 + c) * DD + kk + q * 8);
        bf16x8 bfr;
        #pragma unroll
        for (int j = 0; j < 8; ++j)
            bfr[j] = (bf16_t)W1[(size_t)(kk + q * 8 + j) * HH + col];
        acc = __builtin_amdgcn_mfma_f32_16x16x32_bf16(afr, bfr, acc, 0, 0, 0);
    }
    __shared__ float red[64 * 4];
    if (wv == 1) {
        #pragma unroll
        for (int r = 0; r < 4; ++r) red[lane * 4 + r] = acc[r];
    }
    __syncthreads();
    if (wv == 0) {
        float bias = b1[col];
        #pragma unroll
        for (int r = 0; r < 4; ++r) {
            int m = tm * 16 + q * 4 + r;   // C/D: col=lane&15, row=q*4+r  [m89]
            float v = acc[r] + red[lane * 4 + r] + bias;
            h[(size_t)m * HH + col] = (bf16_t)(v > 0.f ? v : 0.f);
        }
    }
}

// ---------------- Kernel 3: vT8[col][m] = fp8(h @ W_slm + b_slm), transposed
// BK=64 double-buffer (8 steps), phase-staggered k-tile order.
__global__ __launch_bounds__(256) void k_gemm_v(const bf16_t* __restrict__ h,
        const float* __restrict__ Wslm, const float* __restrict__ bslm,
        unsigned char* __restrict__ vT8) {
    __shared__ float wt[2][64 * 64];   // [buf][k=64][col=64] fp32, 2x16 KB
    int t = threadIdx.x;
    int wv = t >> 6, lane = t & 63;
    int c = lane & 15, q = lane >> 4;
    int nb = blockIdx.x * 64;          // 40000 = 625*64, exact
    int col = nb + wv * 16 + c;
    int r  = t >> 4, sg = t & 15;      // stage rows r, r+16, r+32, r+48
    int phase = (blockIdx.x * 5) & 7;
    const float* gbase = Wslm + (size_t)r * VV + nb + sg * 4;

    #define STAGE_V(buf, kk) do { \
        _Pragma("unroll") \
        for (int i = 0; i < 4; ++i) \
            async_ld16(gbase + (size_t)((kk) + 16 * i) * VV, \
                       &wt[buf][t * 4 + i * 1024]); } while (0)

    STAGE_V(0, phase * 64);
    f32x4 acc[8] = {};
    #pragma unroll 1
    for (int step = 0; step < 8; ++step) {
        int cur = step & 1;
        __syncthreads();                       // drains vmcnt -> wt[cur] ready
        if (step < 7) STAGE_V(cur ^ 1, (((step + 1 + phase) & 7) * 64));
        int kk = ((step + phase) & 7) * 64;
        #pragma unroll
        for (int kh = 0; kh < 2; ++kh) {
            bf16x8 bfr;
            #pragma unroll
            for (int j = 0; j < 8; ++j)
                bfr[j] = (bf16_t)wt[cur][(kh * 32 + q * 8 + j) * 64 + wv * 16 + c];
            #pragma unroll
            for (int ms = 0; ms < 8; ++ms) {
                bf16x8 afr = *(const bf16x8*)(h + (size_t)(ms * 16 + c) * HH
                                              + kk + kh * 32 + q * 8);
                acc[ms] = __builtin_amdgcn_mfma_f32_16x16x32_bf16(afr, bfr, acc[ms], 0, 0, 0);
            }
        }
    }
    float bias = bslm[col];
    #pragma unroll
    for (int ms = 0; ms < 8; ++ms) {
        union { unsigned int u; unsigned char b[4]; } pk;
        #pragma unroll
        for (int rr = 0; rr < 4; ++rr) {
            __hip_fp8_e4m3 f8(acc[ms][rr] + bias);
            pk.b[rr] = f8.__x;
        }
        *(unsigned int*)(vT8 + (size_t)col * MM + ms * 16 + q * 4) = pk.u;
    }
    #undef STAGE_V
}

// ---------------- Kernel 4: gather — one wave per s, lane owns 2 m-values.
// slm[s][m] (bf16) = sum_k w[s,k] * fp8dec(vT8[idx[s,k]][m])
__global__ __launch_bounds__(256) void k_gather(const unsigned char* __restrict__ vT8,
        const float* __restrict__ slw, const int* __restrict__ slidx,
        bf16_t* __restrict__ slm) {
    int t = threadIdx.x;
    int wv = t >> 6, lane = t & 63;
    int s = blockIdx.x * 4 + wv;        // 50000 = 12500*4, exact
    int idv = slidx[(size_t)s * KD + (lane & 31)];
    float wgt = slw[(size_t)s * KD + (lane & 31)];
    unsigned short u[KD];
    #pragma unroll
    for (int k = 0; k < KD; ++k) {
        int id = __shfl(idv, k);
        u[k] = *(const unsigned short*)(vT8 + (size_t)id * MM + lane * 2);
    }
    float a0 = 0.f, a1 = 0.f;
    #pragma unroll
    for (int k = 0; k < KD; ++k) {
        float w = __shfl(wgt, k);
        __hip_fp8_e4m3 f0, f1;
        f0.__x = (unsigned char)(u[k] & 0xff);
        f1.__x = (unsigned char)(u[k] >> 8);
        a0 += w * (float)f0;
        a1 += w * (float)f1;
    }
    bf16x2 o;
    o[0] = (bf16_t)a0;
    o[1] = (bf16_t)a1;
    *(bf16x2*)(slm + (size_t)s * MM + lane * 2) = o;
}

// ---------------- Kernel 5: out = h @ W2 + b2 + 0.1 * slm^T
// Same BK=64 staggered structure as k_gemm_v.
__global__ __launch_bounds__(256) void k_gemm_y(const bf16_t* __restrict__ h,
        const float* __restrict__ W2, const float* __restrict__ b2,
        const bf16_t* __restrict__ slm, float* __restrict__ out) {
    __shared__ float wt[2][64 * 64];   // 2x16 KB
    int t = threadIdx.x;
    int wv = t >> 6, lane = t & 63;
    int c = lane & 15, q = lane >> 4;
    int nb = blockIdx.x * 64;
    int col = nb + wv * 16 + c;
    int r  = t >> 4, sg = t & 15;
    int sgc = nb + sg * 4;
    bool ok = (sgc + 4 <= SS);          // clamp for tail block (cols >= SS unused)
    const float* gbase = ok ? (W2 + (size_t)r * SS + sgc) : W2;
    int phase = (blockIdx.x * 5) & 7;

    #define STAGE_Y(buf, kk) do { \
        _Pragma("unroll") \
        for (int i = 0; i < 4; ++i) \
            async_ld16(gbase + (size_t)((kk) + 16 * i) * SS, \
                       &wt[buf][t * 4 + i * 1024]); } while (0)

    STAGE_Y(0, phase * 64);
    f32x4 acc[8] = {};
    #pragma unroll 1
    for (int step = 0; step < 8; ++step) {
        int cur = step & 1;
        __syncthreads();
        if (step < 7) STAGE_Y(cur ^ 1, (((step + 1 + phase) & 7) * 64));
        int kk = ((step + phase) & 7) * 64;
        #pragma unroll
        for (int kh = 0; kh < 2; ++kh) {
            bf16x8 bfr;
            #pragma unroll
            for (int j = 0; j < 8; ++j)
                bfr[j] = (bf16_t)wt[cur][(kh * 32 + q * 8 + j) * 64 + wv * 16 + c];
            #pragma unroll
            for (int ms = 0; ms < 8; ++ms) {
                bf16x8 afr = *(const bf16x8*)(h + (size_t)(ms * 16 + c) * HH
                                              + kk + kh * 32 + q * 8);
                acc[ms] = __builtin_amdgcn_mfma_f32_16x16x32_bf16(afr, bfr, acc[ms], 0, 0, 0);
            }
        }
    }
    if (col < SS) {
        float bias = b2[col];
        #pragma unroll
        for (int ms = 0; ms < 8; ++ms) {
            bf16x4 sv = *(const bf16x4*)(slm + (size_t)col * MM + ms * 16 + q * 4);
            #pragma unroll
            for (int rr = 0; rr < 4; ++rr) {
                int m = ms * 16 + q * 4 + rr;
                out[(size_t)m * SS + col] = acc[ms][rr] + bias + 0.1f * (float)sv[rr];
            }
        }
    }
    #undef STAGE_Y
}

extern "C" void kernel_launch(void* const* d_in, const int* in_sizes, int n_in,
                              void* d_out, int out_size, void* d_ws, size_t ws_size,
                              hipStream_t stream) {
    const float* x     = (const float*)d_in[0];
    const float* gamma = (const float*)d_in[1];
    const float* beta  = (const float*)d_in[2];
    const float* W1    = (const float*)d_in[3];
    const float* b1    = (const float*)d_in[4];
    const float* W2    = (const float*)d_in[5];
    const float* b2    = (const float*)d_in[6];
    const float* Wslm  = (const float*)d_in[7];
    const float* bslm  = (const float*)d_in[8];
    const float* slw   = (const float*)d_in[9];
    const int*   slidx = (const int*)d_in[10];
    float* out = (float*)d_out;

    char* ws = (char*)d_ws;
    bf16_t*        xn  = (bf16_t*)ws;                  // 128*1024*2  = 262144 B
    bf16_t*        h   = (bf16_t*)(ws + 262144);       // 128*512*2   = 131072 B
    unsigned char* vT8 = (unsigned char*)(ws + 393216);// 40000*128   = 5120000 B
    bf16_t*        slm = (bf16_t*)(ws + 5513216);      // 50000*128*2 = 12800000 B

    k_bn    <<<64,    256, 0, stream>>>(x, gamma, beta, xn);
    k_gemm1 <<<256,   128, 0, stream>>>(xn, W1, b1, h);
    k_gemm_v<<<625,   256, 0, stream>>>(h, Wslm, bslm, vT8);
    k_gather<<<12500, 256, 0, stream>>>(vT8, slw, slidx, slm);
    k_gemm_y<<<782,   256, 0, stream>>>(h, W2, b2, slm, out);
}